// Round 2
// baseline (2368.496 us; speedup 1.0000x reference)
//
#include <hip/hip_runtime.h>
#include <math.h>

#define BSZ 4
#define LEN 2048
#define DM 1024
#define DI 2048
#define HD 64      // HEADDIM (p)
#define NH 32      // NHEADS
#define DS 128     // D_STATE (n)
#define CD 2304    // CONV_DIM
#define DP 4384    // D_IN_PROJ
#define NTOK (BSZ*LEN)   // 8192
#define QCH 128          // chunk length
#define NCH (LEN/QCH)    // 16 chunks

// Column offsets inside a zxbcdt row
#define XOFF DI            // 2048: x (heads)
#define BOFF (DI+DI)       // 4096: B
#define COFF (BOFF+DS)     // 4224: C
#define TOFF (DP-NH)       // 4352: dt raw

#define CONV_R 64          // rows per in-place-conv block
#define NRB (NTOK/CONV_R)  // 128 row-blocks

// ---------------------------------------------------------------------------
// Generic fp32 tiled GEMM: C[M,N] = A[M,K] @ B[K,N], row-major with pitches.
// 128x128 tile, BK=32, 256 threads, 8x8 micro-tile (split 4+4 to spread banks).
// ---------------------------------------------------------------------------
__global__ __launch_bounds__(256) void gemm_f32(
    const float* __restrict__ A, const float* __restrict__ B,
    float* __restrict__ C, int M, int N, int K, int lda, int ldb, int ldc)
{
    __shared__ float As[32][132];   // [k][m], padded
    __shared__ float Bs[32][128];   // [k][n]
    const int tid = threadIdx.x;
    const int n0 = blockIdx.x * 128;
    const int m0 = blockIdx.y * 128;
    const int tx = tid & 15;
    const int ty = tid >> 4;
    float acc[8][8];
    #pragma unroll
    for (int i = 0; i < 8; i++)
        #pragma unroll
        for (int j = 0; j < 8; j++) acc[i][j] = 0.f;

    for (int k0 = 0; k0 < K; k0 += 32) {
        #pragma unroll
        for (int i = 0; i < 4; i++) {
            int idx = tid + i * 256;       // 0..1023
            int row = idx >> 3;            // 0..127
            int c4  = idx & 7;             // 0..7 (k quad)
            float4 v = *(const float4*)(A + (size_t)(m0 + row) * lda + k0 + c4 * 4);
            As[c4*4+0][row] = v.x;
            As[c4*4+1][row] = v.y;
            As[c4*4+2][row] = v.z;
            As[c4*4+3][row] = v.w;
        }
        #pragma unroll
        for (int i = 0; i < 4; i++) {
            int idx = tid + i * 256;
            int row = idx >> 5;            // 0..31
            int c4  = idx & 31;            // 0..31
            int col = n0 + c4 * 4;
            float4 v = make_float4(0.f, 0.f, 0.f, 0.f);
            if (col < N) v = *(const float4*)(B + (size_t)(k0 + row) * ldb + col);
            *(float4*)&Bs[row][c4 * 4] = v;
        }
        __syncthreads();
        #pragma unroll
        for (int k = 0; k < 32; k++) {
            float a[8], b[8];
            *(float4*)&a[0] = *(const float4*)&As[k][ty * 4];
            *(float4*)&a[4] = *(const float4*)&As[k][64 + ty * 4];
            *(float4*)&b[0] = *(const float4*)&Bs[k][tx * 4];
            *(float4*)&b[4] = *(const float4*)&Bs[k][64 + tx * 4];
            #pragma unroll
            for (int i = 0; i < 8; i++)
                #pragma unroll
                for (int j = 0; j < 8; j++)
                    acc[i][j] += a[i] * b[j];
        }
        __syncthreads();
    }
    #pragma unroll
    for (int i = 0; i < 8; i++) {
        int row = m0 + ((i < 4) ? (ty * 4 + i) : (64 + ty * 4 + (i - 4)));
        #pragma unroll
        for (int j = 0; j < 8; j += 4) {
            int col = n0 + ((j < 4) ? (tx * 4) : (64 + tx * 4));
            if (col < N) {
                float4 v = make_float4(acc[i][j], acc[i][j+1], acc[i][j+2], acc[i][j+3]);
                *(float4*)(C + (size_t)row * ldc + col) = v;
            }
        }
    }
}

// ---------------------------------------------------------------------------
// Save the 3 raw xBC rows preceding each CONV_R-aligned row-block so the
// in-place conv can read its halo after other blocks overwrite those rows.
// halo[(rb*3 + j)*CD + c] = zx[(rb*CONV_R - 3 + j)*DP + XOFF + c]  (0 at batch start)
// ---------------------------------------------------------------------------
__global__ __launch_bounds__(256) void halo_save(
    const float* __restrict__ zx, float* __restrict__ halo)
{
    size_t idx = (size_t)blockIdx.x * 256 + threadIdx.x;  // < NRB*3*CD
    int c = (int)(idx % CD);
    int r = (int)(idx / CD);          // rb*3 + j
    int j = r % 3;
    int rb = r / 3;
    int row0 = rb * CONV_R;
    float v = 0.f;
    if ((row0 & (LEN - 1)) != 0) {    // not a batch start: halo rows exist
        v = zx[(size_t)(row0 - 3 + j) * DP + XOFF + c];
    }
    halo[idx] = v;
}

// ---------------------------------------------------------------------------
// Depthwise causal conv (width 4) + bias + SiLU, IN-PLACE in zx's xBC slice.
// Each thread owns one channel and walks CONV_R rows keeping 3-reg history.
// grid = (CD/256, NRB). In-place safe: each element read before overwrite,
// halo comes from the snapshot buffer.
// ---------------------------------------------------------------------------
__global__ __launch_bounds__(256) void conv_silu_inplace(
    float* __restrict__ zx, const float* __restrict__ halo,
    const float* __restrict__ cw, const float* __restrict__ cb)
{
    const int c = blockIdx.x * 256 + threadIdx.x;   // channel 0..2303
    const int rb = blockIdx.y;                      // row-block 0..127
    const int row0 = rb * CONV_R;
    const float w0 = cw[c*4+0], w1 = cw[c*4+1], w2 = cw[c*4+2], w3 = cw[c*4+3];
    const float bias = cb[c];
    float h0 = 0.f, h1 = 0.f, h2 = 0.f;             // x[l-3], x[l-2], x[l-1]
    if ((row0 & (LEN - 1)) != 0) {
        h0 = halo[(size_t)(rb*3 + 0) * CD + c];
        h1 = halo[(size_t)(rb*3 + 1) * CD + c];
        h2 = halo[(size_t)(rb*3 + 2) * CD + c];
    }
    float* p = zx + (size_t)row0 * DP + XOFF + c;
    for (int r = 0; r < CONV_R; r++) {
        float xin = *p;
        float acc = bias + w0*h0 + w1*h1 + w2*h2 + w3*xin;
        *p = acc / (1.f + __expf(-acc));
        h0 = h1; h1 = h2; h2 = xin;
        p += DP;
    }
}

// ---------------------------------------------------------------------------
// dt processing: dt' = softplus(raw + bias); ldA = -dt' * exp(A_log)
// ---------------------------------------------------------------------------
__global__ __launch_bounds__(256) void dt_proc(
    const float* __restrict__ zx, const float* __restrict__ dt_bias,
    const float* __restrict__ A_log, float* __restrict__ dtv, float* __restrict__ ldA)
{
    int idx = blockIdx.x * 256 + threadIdx.x;   // t*NH + h
    int h = idx & (NH - 1);
    int t = idx >> 5;
    float v = zx[(size_t)t * DP + TOFF + h] + dt_bias[h];
    float sp = (v > 20.f) ? v : log1pf(expf(v));
    dtv[idx] = sp;
    ldA[idx] = -sp * expf(A_log[h]);
}

// ---------------------------------------------------------------------------
// Phase 1: per (b,h,chunk) compute S[p][n] = sum_s exp(lcpEnd-lcp[s])*dt_s*x[s,p]*B[s,n]
// and chunk log-decay sum. One block per (bh*NCH + chunk). Reads zx in-place slices.
// ---------------------------------------------------------------------------
__global__ __launch_bounds__(256) void phase1(
    const float* __restrict__ zxr, const float* __restrict__ dtv,
    const float* __restrict__ ldA, float* __restrict__ S, float* __restrict__ csum)
{
    const int blk = blockIdx.x;            // bh*NCH + chunk
    const int chunk = blk % NCH;
    const int bh = blk / NCH;
    const int h = bh % NH;
    const int b = bh / NH;
    const int tid = threadIdx.x;
    const size_t rowbase = (size_t)b * LEN + (size_t)chunk * QCH;

    __shared__ float lcp[QCH];
    __shared__ float coef[QCH];
    __shared__ float Xs[16][64];
    __shared__ float Bsm[16][128];

    if (tid < QCH) lcp[tid] = ldA[(rowbase + tid) * NH + h];
    __syncthreads();
    for (int off = 1; off < QCH; off <<= 1) {
        float v = 0.f;
        if (tid < QCH && tid >= off) v = lcp[tid - off];
        __syncthreads();
        if (tid < QCH) lcp[tid] += v;
        __syncthreads();
    }
    if (tid < QCH) coef[tid] = __expf(lcp[QCH - 1] - lcp[tid]) * dtv[(rowbase + tid) * NH + h];
    if (tid == 0) csum[blk] = lcp[QCH - 1];
    __syncthreads();

    const int ts = tid & 31;   // n0 = ts*4
    const int tt = tid >> 5;   // p0 = tt*8
    float acc[8][4];
    #pragma unroll
    for (int i = 0; i < 8; i++)
        #pragma unroll
        for (int j = 0; j < 4; j++) acc[i][j] = 0.f;

    for (int s0 = 0; s0 < QCH; s0 += 16) {
        __syncthreads();
        {   // stage X (16 x 64)
            int s = tid >> 4;
            int p4 = (tid & 15) * 4;
            *(float4*)&Xs[s][p4] = *(const float4*)(zxr + (rowbase + s0 + s) * DP + XOFF + h * HD + p4);
        }
        {   // stage scaled B (16 x 128)
            int s = tid >> 5;
            int n4 = (tid & 31) * 4;
            float c0 = coef[s0 + s];
            float4 v = *(const float4*)(zxr + (rowbase + s0 + s) * DP + BOFF + n4);
            v.x *= c0; v.y *= c0; v.z *= c0; v.w *= c0;
            *(float4*)&Bsm[s][n4] = v;
            int s2 = s + 8;
            float c2 = coef[s0 + s2];
            float4 v2 = *(const float4*)(zxr + (rowbase + s0 + s2) * DP + BOFF + n4);
            v2.x *= c2; v2.y *= c2; v2.z *= c2; v2.w *= c2;
            *(float4*)&Bsm[s2][n4] = v2;
        }
        __syncthreads();
        #pragma unroll
        for (int s = 0; s < 16; s++) {
            float xv[8], bv[4];
            *(float4*)&xv[0] = *(const float4*)&Xs[s][tt * 8];
            *(float4*)&xv[4] = *(const float4*)&Xs[s][tt * 8 + 4];
            *(float4*)&bv[0] = *(const float4*)&Bsm[s][ts * 4];
            #pragma unroll
            for (int i = 0; i < 8; i++)
                #pragma unroll
                for (int j = 0; j < 4; j++)
                    acc[i][j] += xv[i] * bv[j];
        }
    }
    float* Sb = S + (size_t)blk * (HD * DS);
    #pragma unroll
    for (int i = 0; i < 8; i++) {
        float4 v = make_float4(acc[i][0], acc[i][1], acc[i][2], acc[i][3]);
        *(float4*)(Sb + (tt * 8 + i) * DS + ts * 4) = v;
    }
}

// ---------------------------------------------------------------------------
// Phase 2: cross-chunk recurrence. Overwrites S[c] with h_start(chunk c).
// ---------------------------------------------------------------------------
__global__ __launch_bounds__(256) void phase2(
    float* __restrict__ S, const float* __restrict__ csum)
{
    const int bh = blockIdx.x;     // 0..127
    const int tid = threadIdx.x;
    float run[32];
    #pragma unroll
    for (int i = 0; i < 32; i++) run[i] = 0.f;
    for (int c = 0; c < NCH; c++) {
        float P = __expf(csum[bh * NCH + c]);
        float* Sb = S + (size_t)(bh * NCH + c) * (HD * DS);
        #pragma unroll
        for (int i = 0; i < 32; i++) {
            int idx = tid + i * 256;
            float s = Sb[idx];
            Sb[idx] = run[i];              // h_start for this chunk
            run[i] = P * run[i] + s;       // state after this chunk
        }
    }
}

// ---------------------------------------------------------------------------
// Phase 3 (merged): one block per (bh, chunk) computes y for all 128 t.
//   y[t,p] = sum_{s<=t} exp(lcp t - lcp s)*dt_s*(C_t.B_s)*x[s,p]
//          + exp(lcp t) * sum_n C[t,n]*hstart[p,n] + D_h*x[t,p]
// Inter-chunk term read FIRST into registers, then S[bh][chunk] (dead hstart)
// is overwritten with y[t*HD + p]. No other block touches this S region.
// ---------------------------------------------------------------------------
__global__ __launch_bounds__(256) void phase3(
    const float* __restrict__ zxr, const float* __restrict__ dtv,
    const float* __restrict__ ldA, const float* __restrict__ Dvec,
    float* __restrict__ S)
{
    const int tid = threadIdx.x;
    const int blk = blockIdx.x;            // bh*NCH + chunk
    const int chunk = blk % NCH;
    const int bh = blk / NCH;
    const int h = bh % NH;
    const int b = bh / NH;
    const size_t rowbase = (size_t)b * LEN + (size_t)chunk * QCH;

    __shared__ float lcp[QCH];
    __shared__ float dts[QCH];
    __shared__ float Gs[QCH][65];      // [s][t_local]
    __shared__ float Ta[16][64];
    __shared__ float Tb[16][128];

    if (tid < QCH) {
        lcp[tid] = ldA[(rowbase + tid) * NH + h];
        dts[tid] = dtv[(rowbase + tid) * NH + h];
    }
    __syncthreads();
    for (int off = 1; off < QCH; off <<= 1) {
        float v = 0.f;
        if (tid < QCH && tid >= off) v = lcp[tid - off];
        __syncthreads();
        if (tid < QCH) lcp[tid] += v;
        __syncthreads();
    }

    const int tt2 = tid >> 4;   // 0..15 (t micro-tile)
    const int tp  = tid & 15;   // 0..15 (p micro-tile)

    // ---- Step 1: inter[th][i][j] = exp(lcp[t]) * sum_n C[t,n]*hs[p,n]
    //      t = th*64 + tt2*4 + i ; p = tp*4 + j
    float inter[2][4][4];
    #pragma unroll
    for (int a = 0; a < 2; a++)
        #pragma unroll
        for (int i = 0; i < 4; i++)
            #pragma unroll
            for (int j = 0; j < 4; j++) inter[a][i][j] = 0.f;

    const float* hsb = S + (size_t)blk * (HD * DS);
    for (int n0 = 0; n0 < DS; n0 += 16) {
        __syncthreads();
        {
            int t  = tid >> 2;                 // 0..63
            int nq = (tid & 3) * 4;
            const float* cp = zxr + (rowbase + t) * DP + COFF + n0 + nq;
            float sc = __expf(lcp[t]);
            float4 v = *(const float4*)cp;
            Tb[nq+0][t] = v.x * sc; Tb[nq+1][t] = v.y * sc;
            Tb[nq+2][t] = v.z * sc; Tb[nq+3][t] = v.w * sc;
            int t2 = t + 64;
            float sc2 = __expf(lcp[t2]);
            float4 v2 = *(const float4*)(cp + (size_t)64 * DP);
            Tb[nq+0][t2] = v2.x * sc2; Tb[nq+1][t2] = v2.y * sc2;
            Tb[nq+2][t2] = v2.z * sc2; Tb[nq+3][t2] = v2.w * sc2;
            float4 hv = *(const float4*)(hsb + (size_t)t * DS + n0 + nq);
            Ta[nq+0][t] = hv.x; Ta[nq+1][t] = hv.y;
            Ta[nq+2][t] = hv.z; Ta[nq+3][t] = hv.w;
        }
        __syncthreads();
        #pragma unroll
        for (int np = 0; np < 16; np++) {
            float hv[4];
            *(float4*)hv = *(const float4*)&Ta[np][tp * 4];
            #pragma unroll
            for (int th = 0; th < 2; th++)
                #pragma unroll
                for (int i = 0; i < 4; i++) {
                    float cv = Tb[np][th * 64 + tt2 * 4 + i];
                    #pragma unroll
                    for (int j = 0; j < 4; j++) inter[th][i][j] += cv * hv[j];
                }
        }
    }

    const float Dh = Dvec[h];
    float* yb = S + (size_t)blk * (HD * DS);

    // ---- Step 2: two t-halves
    for (int th = 0; th < 2; th++) {
        const int tbase = th * 64;
        const int sMax = tbase + 64;

        // G[t_local][s] = C_t.B_s (K=128 over n), weighted+masked
        {
            const int ts = tid & 31;    // s0 = ts*4
            const int tt = tid >> 5;    // t0 = tt*8 (local)
            float acc[8][4];
            #pragma unroll
            for (int i = 0; i < 8; i++)
                #pragma unroll
                for (int j = 0; j < 4; j++) acc[i][j] = 0.f;

            for (int n0 = 0; n0 < DS; n0 += 16) {
                __syncthreads();
                {
                    int t  = tid >> 2;             // 0..63
                    int nq = (tid & 3) * 4;
                    float4 v = *(const float4*)(zxr + (rowbase + tbase + t) * DP + COFF + n0 + nq);
                    Ta[nq+0][t] = v.x; Ta[nq+1][t] = v.y;
                    Ta[nq+2][t] = v.z; Ta[nq+3][t] = v.w;
                    float4 vb = *(const float4*)(zxr + (rowbase + t) * DP + BOFF + n0 + nq);
                    Tb[nq+0][t] = vb.x; Tb[nq+1][t] = vb.y;
                    Tb[nq+2][t] = vb.z; Tb[nq+3][t] = vb.w;
                    int s2 = t + 64;
                    float4 vb2 = *(const float4*)(zxr + (rowbase + s2) * DP + BOFF + n0 + nq);
                    Tb[nq+0][s2] = vb2.x; Tb[nq+1][s2] = vb2.y;
                    Tb[nq+2][s2] = vb2.z; Tb[nq+3][s2] = vb2.w;
                }
                __syncthreads();
                #pragma unroll
                for (int np = 0; np < 16; np++) {
                    float cv[8], bv[4];
                    *(float4*)&cv[0] = *(const float4*)&Ta[np][tt * 8];
                    *(float4*)&cv[4] = *(const float4*)&Ta[np][tt * 8 + 4];
                    *(float4*)&bv[0] = *(const float4*)&Tb[np][ts * 4];
                    #pragma unroll
                    for (int i = 0; i < 8; i++)
                        #pragma unroll
                        for (int j = 0; j < 4; j++)
                            acc[i][j] += cv[i] * bv[j];
                }
            }
            #pragma unroll
            for (int i = 0; i < 8; i++) {
                int tl = tt * 8 + i;
                int tg = tbase + tl;
                float lt = lcp[tg];
                #pragma unroll
                for (int j = 0; j < 4; j++) {
                    int s = ts * 4 + j;
                    float w = (s <= tg) ? (__expf(lt - lcp[s]) * dts[s]) : 0.f;
                    Gs[s][tl] = acc[i][j] * w;
                }
            }
        }
        __syncthreads();

        // Y = G @ X (+ inter + D*x), write into S region (dead hstart)
        float acc2[4][4];
        #pragma unroll
        for (int i = 0; i < 4; i++)
            #pragma unroll
            for (int j = 0; j < 4; j++) acc2[i][j] = 0.f;

        for (int s0 = 0; s0 < sMax; s0 += 16) {
            __syncthreads();
            {
                int s = tid >> 4;
                int p4 = (tid & 15) * 4;
                *(float4*)&Ta[s][p4] = *(const float4*)(zxr + (rowbase + s0 + s) * DP + XOFF + h * HD + p4);
            }
            __syncthreads();
            #pragma unroll
            for (int s = 0; s < 16; s++) {
                float xv[4];
                *(float4*)xv = *(const float4*)&Ta[s][tp * 4];
                float g0 = Gs[s0 + s][tt2 * 4 + 0];
                float g1 = Gs[s0 + s][tt2 * 4 + 1];
                float g2 = Gs[s0 + s][tt2 * 4 + 2];
                float g3 = Gs[s0 + s][tt2 * 4 + 3];
                #pragma unroll
                for (int j = 0; j < 4; j++) {
                    acc2[0][j] += g0 * xv[j];
                    acc2[1][j] += g1 * xv[j];
                    acc2[2][j] += g2 * xv[j];
                    acc2[3][j] += g3 * xv[j];
                }
            }
        }

        #pragma unroll
        for (int i = 0; i < 4; i++) {
            int tl = tt2 * 4 + i;
            int t = tbase + tl;
            float4 xv = *(const float4*)(zxr + (rowbase + t) * DP + XOFF + h * HD + tp * 4);
            float4 o;
            o.x = acc2[i][0] + inter[th][i][0] + Dh * xv.x;
            o.y = acc2[i][1] + inter[th][i][1] + Dh * xv.y;
            o.z = acc2[i][2] + inter[th][i][2] + Dh * xv.z;
            o.w = acc2[i][3] + inter[th][i][3] + Dh * xv.w;
            *(float4*)(yb + (size_t)t * HD + tp * 4) = o;
        }
    }
}

// ---------------------------------------------------------------------------
// Gate (y * silu(z)) + RMSNorm over DI. y gathered from S layout; result
// written in-place into the z slice of zx (becomes GEMM2 input).
// ---------------------------------------------------------------------------
__global__ __launch_bounds__(256) void gate_rms(
    float* __restrict__ zx, const float* __restrict__ Sy, const float* __restrict__ nw)
{
    const int row = blockIdx.x;            // token 0..8191
    const int tid = threadIdx.x;
    const int b = row >> 11;               // LEN = 2048
    const int l = row & (LEN - 1);
    const int chunk = l >> 7;
    const int t = l & (QCH - 1);
    float* zr = zx + (size_t)row * DP;
    float g[8];
    float ss = 0.f;
    #pragma unroll
    for (int i = 0; i < 8; i++) {
        int c = tid + i * 256;
        int h = c >> 6;
        int p = c & 63;
        float y = Sy[((size_t)((b * NH + h) * NCH + chunk)) * (HD * DS) + t * HD + p];
        float z = zr[c];
        float sg = z / (1.f + __expf(-z));
        float v = y * sg;
        g[i] = v;
        ss += v * v;
    }
    #pragma unroll
    for (int off = 32; off > 0; off >>= 1) ss += __shfl_down(ss, off, 64);
    __shared__ float red[4];
    if ((tid & 63) == 0) red[tid >> 6] = ss;
    __syncthreads();
    float tot = red[0] + red[1] + red[2] + red[3];
    float r = rsqrtf(tot * (1.f / DI) + 1e-5f);
    #pragma unroll
    for (int i = 0; i < 8; i++) {
        int c = tid + i * 256;
        zr[c] = g[i] * r * nw[c];
    }
}

// ---------------------------------------------------------------------------
extern "C" void kernel_launch(void* const* d_in, const int* in_sizes, int n_in,
                              void* d_out, int out_size, void* d_ws, size_t ws_size,
                              hipStream_t stream)
{
    const float* hidden  = (const float*)d_in[0];
    const float* W_in    = (const float*)d_in[1];
    const float* conv_w  = (const float*)d_in[2];
    const float* conv_b  = (const float*)d_in[3];
    const float* dt_bias = (const float*)d_in[4];
    const float* A_log   = (const float*)d_in[5];
    const float* Dv      = (const float*)d_in[6];
    const float* norm_w  = (const float*)d_in[7];
    const float* W_out   = (const float*)d_in[8];
    float* out = (float*)d_out;

    char* ws = (char*)d_ws;
    size_t o = 0;
    float* zx   = (float*)(ws + o); o += (size_t)NTOK * DP * 4;                  // 143.7 MB
    float* S    = (float*)(ws + o); o += (size_t)BSZ * NH * NCH * HD * DS * 4;   // 67.1 MB
    float* dtv  = (float*)(ws + o); o += (size_t)NTOK * NH * 4;                  // 1.05 MB
    float* ldA  = (float*)(ws + o); o += (size_t)NTOK * NH * 4;                  // 1.05 MB
    float* csum = (float*)(ws + o); o += (size_t)BSZ * NH * NCH * 4;             // 8 KB
    float* halo = (float*)(ws + o); o += (size_t)NRB * 3 * CD * 4;               // 3.5 MB
    // total ~216.4 MB

    // 1) zxbcdt = hidden @ W_in
    gemm_f32<<<dim3((DP + 127) / 128, NTOK / 128), 256, 0, stream>>>(
        hidden, W_in, zx, NTOK, DP, DM, DM, DP, DP);
    // 2a) snapshot conv halos, 2b) causal conv + SiLU in-place in zx's xBC slice
    halo_save<<<(NRB * 3 * CD) / 256, 256, 0, stream>>>(zx, halo);
    conv_silu_inplace<<<dim3(CD / 256, NRB), 256, 0, stream>>>(zx, halo, conv_w, conv_b);
    // 3) dt softplus + log decay
    dt_proc<<<(NTOK * NH) / 256, 256, 0, stream>>>(zx, dt_bias, A_log, dtv, ldA);
    // 4) chunk state contributions
    phase1<<<BSZ * NH * NCH, 256, 0, stream>>>(zx, dtv, ldA, S, csum);
    // 5) cross-chunk recurrence (S -> h_start per chunk)
    phase2<<<BSZ * NH, 256, 0, stream>>>(S, csum);
    // 6) per-chunk outputs (overwrites S with y)
    phase3<<<BSZ * NH * NCH, 256, 0, stream>>>(zx, dtv, ldA, Dv, S);
    // 7) gate + RMSNorm (in-place into z slice)
    gate_rms<<<NTOK, 256, 0, stream>>>(zx, S, norm_w);
    // 8) out = y_norm @ W_out
    gemm_f32<<<dim3(DM / 128, NTOK / 128), 256, 0, stream>>>(
        zx, W_out, out, NTOK, DM, DI, DP, DM, DM);
}

// Round 3
// 751.102 us; speedup vs baseline: 3.1534x; 3.1534x over previous
//
#include <hip/hip_runtime.h>
#include <math.h>

#define BSZ 4
#define LEN 2048
#define DM 1024
#define DI 2048
#define HD 64      // HEADDIM (p)
#define NH 32      // NHEADS
#define DS 128     // D_STATE (n)
#define CD 2304    // CONV_DIM
#define DP 4384    // D_IN_PROJ
#define NTOK (BSZ*LEN)   // 8192
#define QCH 128          // chunk length
#define NCH (LEN/QCH)    // 16 chunks

// Column offsets inside a zxbcdt row
#define XOFF DI            // 2048: x (heads)
#define BOFF (DI+DI)       // 4096: B
#define COFF (BOFF+DS)     // 4224: C
#define TOFF (DP-NH)       // 4352: dt raw

#define CONV_R 64          // rows per in-place-conv block
#define NRB (NTOK/CONV_R)  // 128 row-blocks

#define NPAD 4480          // W_in columns padded to 35*128

typedef unsigned short ushort_t;
typedef __bf16 bf16x8 __attribute__((ext_vector_type(8)));
typedef float f32x4 __attribute__((ext_vector_type(4)));

__device__ __forceinline__ ushort_t f2bf(float f) {
    unsigned u = __float_as_uint(f);
    unsigned r = (u + 0x7FFFu + ((u >> 16) & 1u)) >> 16;
    return (ushort_t)r;
}

__device__ __forceinline__ void gl_lds16(const void* g, void* l) {
    __builtin_amdgcn_global_load_lds(
        (const __attribute__((address_space(1))) void*)g,
        (__attribute__((address_space(3))) void*)l, 16, 0, 0);
}

// ---------------------------------------------------------------------------
// fp32 -> bf16 elementwise (hidden). 4 elems/thread.
// ---------------------------------------------------------------------------
__global__ __launch_bounds__(256) void cvt_bf16(
    const float* __restrict__ A, ushort_t* __restrict__ Ab)
{
    size_t i = ((size_t)blockIdx.x * 256 + threadIdx.x) * 4;
    float4 v = *(const float4*)(A + i);
    ushort_t o[4] = { f2bf(v.x), f2bf(v.y), f2bf(v.z), f2bf(v.w) };
    *(uint2*)(Ab + i) = *(uint2*)o;
}

// ---------------------------------------------------------------------------
// W[k][n] fp32 (ld=ldw) -> Wt[n][k] bf16 (ld=K), zero-pad for n >= N.
// grid = (Np/32, K/32), 256 threads, LDS 32x33 tile.
// ---------------------------------------------------------------------------
__global__ __launch_bounds__(256) void transpose_cvt(
    const float* __restrict__ W, ushort_t* __restrict__ Wt,
    int K, int N, int ldw)
{
    __shared__ float T[32][33];
    const int n0 = blockIdx.x * 32;
    const int k0 = blockIdx.y * 32;
    const int tid = threadIdx.x;
    #pragma unroll
    for (int l = 0; l < 4; l++) {
        int idx = tid + l * 256;
        int ki = idx >> 5, nj = idx & 31;
        int n = n0 + nj;
        T[ki][nj] = (n < N) ? W[(size_t)(k0 + ki) * ldw + n] : 0.f;
    }
    __syncthreads();
    #pragma unroll
    for (int l = 0; l < 4; l++) {
        int idx = tid + l * 256;
        int nj = idx >> 5, ki = idx & 31;
        Wt[(size_t)(n0 + nj) * K + k0 + ki] = f2bf(T[ki][nj]);
    }
}

// ---------------------------------------------------------------------------
// bf16 MFMA GEMM (B^T form): C[m][n] = sum_k A[m][k] * Bt[n][k].
// 128x128 tile, BK=32, 4 waves in 2x2, 4x4 frags of 16x16x32 MFMA per wave.
// global_load_lds width-16 staging (m97 structure). fp32 out with col guard.
// ---------------------------------------------------------------------------
__global__ __launch_bounds__(256) void gemm_bf16(
    const ushort_t* __restrict__ A, const ushort_t* __restrict__ Bt,
    float* __restrict__ C, int K, int lda, int ldb, int ldc, int nmax)
{
    __shared__ __align__(16) ushort_t As[128 * 32];
    __shared__ __align__(16) ushort_t Bs[128 * 32];
    const int tid = threadIdx.x;
    const int n0 = blockIdx.x * 128;
    const int m0 = blockIdx.y * 128;
    const int lane = tid & 63;
    const int w = tid >> 6;
    const int wm = w >> 1, wn = w & 1;
    const int lm = lane & 15, quad = lane >> 4;

    const int srow = tid >> 2;          // 0..63
    const int skq = (tid & 3) * 8;      // k elem offset, 16B chunks
    const ushort_t* ga0 = A + (size_t)(m0 + srow) * lda + skq;
    const ushort_t* ga1 = A + (size_t)(m0 + 64 + srow) * lda + skq;
    const ushort_t* gb0 = Bt + (size_t)(n0 + srow) * ldb + skq;
    const ushort_t* gb1 = Bt + (size_t)(n0 + 64 + srow) * ldb + skq;
    ushort_t* la0 = &As[srow * 32 + skq];
    ushort_t* la1 = &As[(64 + srow) * 32 + skq];
    ushort_t* lb0 = &Bs[srow * 32 + skq];
    ushort_t* lb1 = &Bs[(64 + srow) * 32 + skq];

    f32x4 acc[4][4];
    #pragma unroll
    for (int i = 0; i < 4; i++)
        #pragma unroll
        for (int j = 0; j < 4; j++) acc[i][j] = (f32x4){0.f, 0.f, 0.f, 0.f};

    for (int k0 = 0; k0 < K; k0 += 32) {
        gl_lds16(ga0, la0);
        gl_lds16(ga1, la1);
        gl_lds16(gb0, lb0);
        gl_lds16(gb1, lb1);
        ga0 += 32; ga1 += 32; gb0 += 32; gb1 += 32;
        __syncthreads();
        bf16x8 af[4], bfr[4];
        #pragma unroll
        for (int i = 0; i < 4; i++)
            af[i] = *(const bf16x8*)&As[(wm * 64 + i * 16 + lm) * 32 + quad * 8];
        #pragma unroll
        for (int j = 0; j < 4; j++)
            bfr[j] = *(const bf16x8*)&Bs[(wn * 64 + j * 16 + lm) * 32 + quad * 8];
        #pragma unroll
        for (int i = 0; i < 4; i++)
            #pragma unroll
            for (int j = 0; j < 4; j++)
                acc[i][j] = __builtin_amdgcn_mfma_f32_16x16x32_bf16(af[i], bfr[j], acc[i][j], 0, 0, 0);
        __syncthreads();
    }

    #pragma unroll
    for (int i = 0; i < 4; i++) {
        int row = m0 + wm * 64 + i * 16 + quad * 4;
        #pragma unroll
        for (int j = 0; j < 4; j++) {
            int col = n0 + wn * 64 + j * 16 + lm;
            if (col < nmax) {
                #pragma unroll
                for (int r = 0; r < 4; r++)
                    C[(size_t)(row + r) * ldc + col] = acc[i][j][r];
            }
        }
    }
}

// ---------------------------------------------------------------------------
// Save the 3 raw xBC rows preceding each CONV_R-aligned row-block.
// ---------------------------------------------------------------------------
__global__ __launch_bounds__(256) void halo_save(
    const float* __restrict__ zx, float* __restrict__ halo)
{
    size_t idx = (size_t)blockIdx.x * 256 + threadIdx.x;  // < NRB*3*CD
    int c = (int)(idx % CD);
    int r = (int)(idx / CD);
    int j = r % 3;
    int rb = r / 3;
    int row0 = rb * CONV_R;
    float v = 0.f;
    if ((row0 & (LEN - 1)) != 0) {
        v = zx[(size_t)(row0 - 3 + j) * DP + XOFF + c];
    }
    halo[idx] = v;
}

// ---------------------------------------------------------------------------
// Depthwise causal conv (width 4) + bias + SiLU, IN-PLACE in zx's xBC slice.
// ---------------------------------------------------------------------------
__global__ __launch_bounds__(256) void conv_silu_inplace(
    float* __restrict__ zx, const float* __restrict__ halo,
    const float* __restrict__ cw, const float* __restrict__ cb)
{
    const int c = blockIdx.x * 256 + threadIdx.x;
    const int rb = blockIdx.y;
    const int row0 = rb * CONV_R;
    const float w0 = cw[c*4+0], w1 = cw[c*4+1], w2 = cw[c*4+2], w3 = cw[c*4+3];
    const float bias = cb[c];
    float h0 = 0.f, h1 = 0.f, h2 = 0.f;
    if ((row0 & (LEN - 1)) != 0) {
        h0 = halo[(size_t)(rb*3 + 0) * CD + c];
        h1 = halo[(size_t)(rb*3 + 1) * CD + c];
        h2 = halo[(size_t)(rb*3 + 2) * CD + c];
    }
    float* p = zx + (size_t)row0 * DP + XOFF + c;
    for (int r = 0; r < CONV_R; r++) {
        float xin = *p;
        float acc = bias + w0*h0 + w1*h1 + w2*h2 + w3*xin;
        *p = acc / (1.f + __expf(-acc));
        h0 = h1; h1 = h2; h2 = xin;
        p += DP;
    }
}

// ---------------------------------------------------------------------------
// dt in FULL fp32 straight from hidden @ W_in[:, TOFF:TOFF+NH] (bypasses the
// bf16 GEMM — dt feeds exp() with gain up to 16, the one nonlinear amplifier).
// Block = 8 tokens x 32 heads.
// ---------------------------------------------------------------------------
__global__ __launch_bounds__(256) void dt_proc_fp32(
    const float* __restrict__ hidden, const float* __restrict__ W_in,
    const float* __restrict__ dt_bias, const float* __restrict__ A_log,
    float* __restrict__ dtv, float* __restrict__ ldA)
{
    const int h = threadIdx.x & 31;
    const int tt = threadIdx.x >> 5;
    const int t = blockIdx.x * 8 + tt;
    const float* hr = hidden + (size_t)t * DM;
    const float* wc = W_in + TOFF + h;
    float acc = 0.f;
    #pragma unroll 4
    for (int k = 0; k < DM; k++) acc += hr[k] * wc[(size_t)k * DP];
    float v = acc + dt_bias[h];
    float sp = (v > 20.f) ? v : log1pf(expf(v));
    int idx = t * NH + h;
    dtv[idx] = sp;
    ldA[idx] = -sp * expf(A_log[h]);
}

// ---------------------------------------------------------------------------
// Phase 1: per (b,h,chunk) S[p][n] = sum_s exp(lcpEnd-lcp[s])*dt_s*x[s,p]*B[s,n]
// ---------------------------------------------------------------------------
__global__ __launch_bounds__(256) void phase1(
    const float* __restrict__ zxr, const float* __restrict__ dtv,
    const float* __restrict__ ldA, float* __restrict__ S, float* __restrict__ csum)
{
    const int blk = blockIdx.x;
    const int chunk = blk % NCH;
    const int bh = blk / NCH;
    const int h = bh % NH;
    const int b = bh / NH;
    const int tid = threadIdx.x;
    const size_t rowbase = (size_t)b * LEN + (size_t)chunk * QCH;

    __shared__ float lcp[QCH];
    __shared__ float coef[QCH];
    __shared__ float Xs[16][64];
    __shared__ float Bsm[16][128];

    if (tid < QCH) lcp[tid] = ldA[(rowbase + tid) * NH + h];
    __syncthreads();
    for (int off = 1; off < QCH; off <<= 1) {
        float v = 0.f;
        if (tid < QCH && tid >= off) v = lcp[tid - off];
        __syncthreads();
        if (tid < QCH) lcp[tid] += v;
        __syncthreads();
    }
    if (tid < QCH) coef[tid] = __expf(lcp[QCH - 1] - lcp[tid]) * dtv[(rowbase + tid) * NH + h];
    if (tid == 0) csum[blk] = lcp[QCH - 1];
    __syncthreads();

    const int ts = tid & 31;
    const int tt = tid >> 5;
    float acc[8][4];
    #pragma unroll
    for (int i = 0; i < 8; i++)
        #pragma unroll
        for (int j = 0; j < 4; j++) acc[i][j] = 0.f;

    for (int s0 = 0; s0 < QCH; s0 += 16) {
        __syncthreads();
        {
            int s = tid >> 4;
            int p4 = (tid & 15) * 4;
            *(float4*)&Xs[s][p4] = *(const float4*)(zxr + (rowbase + s0 + s) * DP + XOFF + h * HD + p4);
        }
        {
            int s = tid >> 5;
            int n4 = (tid & 31) * 4;
            float c0 = coef[s0 + s];
            float4 v = *(const float4*)(zxr + (rowbase + s0 + s) * DP + BOFF + n4);
            v.x *= c0; v.y *= c0; v.z *= c0; v.w *= c0;
            *(float4*)&Bsm[s][n4] = v;
            int s2 = s + 8;
            float c2 = coef[s0 + s2];
            float4 v2 = *(const float4*)(zxr + (rowbase + s0 + s2) * DP + BOFF + n4);
            v2.x *= c2; v2.y *= c2; v2.z *= c2; v2.w *= c2;
            *(float4*)&Bsm[s2][n4] = v2;
        }
        __syncthreads();
        #pragma unroll
        for (int s = 0; s < 16; s++) {
            float xv[8], bv[4];
            *(float4*)&xv[0] = *(const float4*)&Xs[s][tt * 8];
            *(float4*)&xv[4] = *(const float4*)&Xs[s][tt * 8 + 4];
            *(float4*)&bv[0] = *(const float4*)&Bsm[s][ts * 4];
            #pragma unroll
            for (int i = 0; i < 8; i++)
                #pragma unroll
                for (int j = 0; j < 4; j++)
                    acc[i][j] += xv[i] * bv[j];
        }
    }
    float* Sb = S + (size_t)blk * (HD * DS);
    #pragma unroll
    for (int i = 0; i < 8; i++) {
        float4 v = make_float4(acc[i][0], acc[i][1], acc[i][2], acc[i][3]);
        *(float4*)(Sb + (tt * 8 + i) * DS + ts * 4) = v;
    }
}

// ---------------------------------------------------------------------------
// Phase 2: cross-chunk recurrence. Overwrites S[c] with h_start(chunk c).
// ---------------------------------------------------------------------------
__global__ __launch_bounds__(256) void phase2(
    float* __restrict__ S, const float* __restrict__ csum)
{
    const int bh = blockIdx.x;
    const int tid = threadIdx.x;
    float run[32];
    #pragma unroll
    for (int i = 0; i < 32; i++) run[i] = 0.f;
    for (int c = 0; c < NCH; c++) {
        float P = __expf(csum[bh * NCH + c]);
        float* Sb = S + (size_t)(bh * NCH + c) * (HD * DS);
        #pragma unroll
        for (int i = 0; i < 32; i++) {
            int idx = tid + i * 256;
            float s = Sb[idx];
            Sb[idx] = run[i];
            run[i] = P * run[i] + s;
        }
    }
}

// ---------------------------------------------------------------------------
// Phase 3: one block per (bh, chunk) computes y for all 128 t; writes y over
// its own (dead) S region.
// ---------------------------------------------------------------------------
__global__ __launch_bounds__(256) void phase3(
    const float* __restrict__ zxr, const float* __restrict__ dtv,
    const float* __restrict__ ldA, const float* __restrict__ Dvec,
    float* __restrict__ S)
{
    const int tid = threadIdx.x;
    const int blk = blockIdx.x;
    const int chunk = blk % NCH;
    const int bh = blk / NCH;
    const int h = bh % NH;
    const int b = bh / NH;
    const size_t rowbase = (size_t)b * LEN + (size_t)chunk * QCH;

    __shared__ float lcp[QCH];
    __shared__ float dts[QCH];
    __shared__ float Gs[QCH][65];
    __shared__ float Ta[16][64];
    __shared__ float Tb[16][128];

    if (tid < QCH) {
        lcp[tid] = ldA[(rowbase + tid) * NH + h];
        dts[tid] = dtv[(rowbase + tid) * NH + h];
    }
    __syncthreads();
    for (int off = 1; off < QCH; off <<= 1) {
        float v = 0.f;
        if (tid < QCH && tid >= off) v = lcp[tid - off];
        __syncthreads();
        if (tid < QCH) lcp[tid] += v;
        __syncthreads();
    }

    const int tt2 = tid >> 4;
    const int tp  = tid & 15;

    float inter[2][4][4];
    #pragma unroll
    for (int a = 0; a < 2; a++)
        #pragma unroll
        for (int i = 0; i < 4; i++)
            #pragma unroll
            for (int j = 0; j < 4; j++) inter[a][i][j] = 0.f;

    const float* hsb = S + (size_t)blk * (HD * DS);
    for (int n0 = 0; n0 < DS; n0 += 16) {
        __syncthreads();
        {
            int t  = tid >> 2;
            int nq = (tid & 3) * 4;
            const float* cp = zxr + (rowbase + t) * DP + COFF + n0 + nq;
            float sc = __expf(lcp[t]);
            float4 v = *(const float4*)cp;
            Tb[nq+0][t] = v.x * sc; Tb[nq+1][t] = v.y * sc;
            Tb[nq+2][t] = v.z * sc; Tb[nq+3][t] = v.w * sc;
            int t2 = t + 64;
            float sc2 = __expf(lcp[t2]);
            float4 v2 = *(const float4*)(cp + (size_t)64 * DP);
            Tb[nq+0][t2] = v2.x * sc2; Tb[nq+1][t2] = v2.y * sc2;
            Tb[nq+2][t2] = v2.z * sc2; Tb[nq+3][t2] = v2.w * sc2;
            float4 hv = *(const float4*)(hsb + (size_t)t * DS + n0 + nq);
            Ta[nq+0][t] = hv.x; Ta[nq+1][t] = hv.y;
            Ta[nq+2][t] = hv.z; Ta[nq+3][t] = hv.w;
        }
        __syncthreads();
        #pragma unroll
        for (int np = 0; np < 16; np++) {
            float hv[4];
            *(float4*)hv = *(const float4*)&Ta[np][tp * 4];
            #pragma unroll
            for (int th = 0; th < 2; th++)
                #pragma unroll
                for (int i = 0; i < 4; i++) {
                    float cv = Tb[np][th * 64 + tt2 * 4 + i];
                    #pragma unroll
                    for (int j = 0; j < 4; j++) inter[th][i][j] += cv * hv[j];
                }
        }
    }

    const float Dh = Dvec[h];
    float* yb = S + (size_t)blk * (HD * DS);

    for (int th = 0; th < 2; th++) {
        const int tbase = th * 64;
        const int sMax = tbase + 64;

        {
            const int ts = tid & 31;
            const int tt = tid >> 5;
            float acc[8][4];
            #pragma unroll
            for (int i = 0; i < 8; i++)
                #pragma unroll
                for (int j = 0; j < 4; j++) acc[i][j] = 0.f;

            for (int n0 = 0; n0 < DS; n0 += 16) {
                __syncthreads();
                {
                    int t  = tid >> 2;
                    int nq = (tid & 3) * 4;
                    float4 v = *(const float4*)(zxr + (rowbase + tbase + t) * DP + COFF + n0 + nq);
                    Ta[nq+0][t] = v.x; Ta[nq+1][t] = v.y;
                    Ta[nq+2][t] = v.z; Ta[nq+3][t] = v.w;
                    float4 vb = *(const float4*)(zxr + (rowbase + t) * DP + BOFF + n0 + nq);
                    Tb[nq+0][t] = vb.x; Tb[nq+1][t] = vb.y;
                    Tb[nq+2][t] = vb.z; Tb[nq+3][t] = vb.w;
                    int s2 = t + 64;
                    float4 vb2 = *(const float4*)(zxr + (rowbase + s2) * DP + BOFF + n0 + nq);
                    Tb[nq+0][s2] = vb2.x; Tb[nq+1][s2] = vb2.y;
                    Tb[nq+2][s2] = vb2.z; Tb[nq+3][s2] = vb2.w;
                }
                __syncthreads();
                #pragma unroll
                for (int np = 0; np < 16; np++) {
                    float cv[8], bv[4];
                    *(float4*)&cv[0] = *(const float4*)&Ta[np][tt * 8];
                    *(float4*)&cv[4] = *(const float4*)&Ta[np][tt * 8 + 4];
                    *(float4*)&bv[0] = *(const float4*)&Tb[np][ts * 4];
                    #pragma unroll
                    for (int i = 0; i < 8; i++)
                        #pragma unroll
                        for (int j = 0; j < 4; j++)
                            acc[i][j] += cv[i] * bv[j];
                }
            }
            #pragma unroll
            for (int i = 0; i < 8; i++) {
                int tl = tt * 8 + i;
                int tg = tbase + tl;
                float lt = lcp[tg];
                #pragma unroll
                for (int j = 0; j < 4; j++) {
                    int s = ts * 4 + j;
                    float wv = (s <= tg) ? (__expf(lt - lcp[s]) * dts[s]) : 0.f;
                    Gs[s][tl] = acc[i][j] * wv;
                }
            }
        }
        __syncthreads();

        float acc2[4][4];
        #pragma unroll
        for (int i = 0; i < 4; i++)
            #pragma unroll
            for (int j = 0; j < 4; j++) acc2[i][j] = 0.f;

        for (int s0 = 0; s0 < sMax; s0 += 16) {
            __syncthreads();
            {
                int s = tid >> 4;
                int p4 = (tid & 15) * 4;
                *(float4*)&Ta[s][p4] = *(const float4*)(zxr + (rowbase + s0 + s) * DP + XOFF + h * HD + p4);
            }
            __syncthreads();
            #pragma unroll
            for (int s = 0; s < 16; s++) {
                float xv[4];
                *(float4*)xv = *(const float4*)&Ta[s][tp * 4];
                float g0 = Gs[s0 + s][tt2 * 4 + 0];
                float g1 = Gs[s0 + s][tt2 * 4 + 1];
                float g2 = Gs[s0 + s][tt2 * 4 + 2];
                float g3 = Gs[s0 + s][tt2 * 4 + 3];
                #pragma unroll
                for (int j = 0; j < 4; j++) {
                    acc2[0][j] += g0 * xv[j];
                    acc2[1][j] += g1 * xv[j];
                    acc2[2][j] += g2 * xv[j];
                    acc2[3][j] += g3 * xv[j];
                }
            }
        }

        #pragma unroll
        for (int i = 0; i < 4; i++) {
            int tl = tt2 * 4 + i;
            int t = tbase + tl;
            float4 xv = *(const float4*)(zxr + (rowbase + t) * DP + XOFF + h * HD + tp * 4);
            float4 o;
            o.x = acc2[i][0] + inter[th][i][0] + Dh * xv.x;
            o.y = acc2[i][1] + inter[th][i][1] + Dh * xv.y;
            o.z = acc2[i][2] + inter[th][i][2] + Dh * xv.z;
            o.w = acc2[i][3] + inter[th][i][3] + Dh * xv.w;
            *(float4*)(yb + (size_t)t * HD + tp * 4) = o;
        }
    }
}

// ---------------------------------------------------------------------------
// Gate (y * silu(z)) + RMSNorm over DI. Writes y_norm as BF16 into zx's dead
// xBC slice (becomes GEMM2's A operand: base (ushort*)zx + 2*XOFF, lda=2*DP).
// ---------------------------------------------------------------------------
__global__ __launch_bounds__(256) void gate_rms(
    float* __restrict__ zx, const float* __restrict__ Sy, const float* __restrict__ nw)
{
    const int row = blockIdx.x;
    const int tid = threadIdx.x;
    const int b = row >> 11;
    const int l = row & (LEN - 1);
    const int chunk = l >> 7;
    const int t = l & (QCH - 1);
    float* zr = zx + (size_t)row * DP;
    ushort_t* ysl = (ushort_t*)(zr + XOFF);
    float g[8];
    float ss = 0.f;
    #pragma unroll
    for (int i = 0; i < 8; i++) {
        int c = tid + i * 256;
        int h = c >> 6;
        int p = c & 63;
        float y = Sy[((size_t)((b * NH + h) * NCH + chunk)) * (HD * DS) + t * HD + p];
        float z = zr[c];
        float sg = z / (1.f + __expf(-z));
        float v = y * sg;
        g[i] = v;
        ss += v * v;
    }
    #pragma unroll
    for (int off = 32; off > 0; off >>= 1) ss += __shfl_down(ss, off, 64);
    __shared__ float red[4];
    if ((tid & 63) == 0) red[tid >> 6] = ss;
    __syncthreads();
    float tot = red[0] + red[1] + red[2] + red[3];
    float r = rsqrtf(tot * (1.f / DI) + 1e-5f);
    #pragma unroll
    for (int i = 0; i < 8; i++) {
        int c = tid + i * 256;
        ysl[c] = f2bf(g[i] * r * nw[c]);
    }
}

// ---------------------------------------------------------------------------
extern "C" void kernel_launch(void* const* d_in, const int* in_sizes, int n_in,
                              void* d_out, int out_size, void* d_ws, size_t ws_size,
                              hipStream_t stream)
{
    const float* hidden  = (const float*)d_in[0];
    const float* W_in    = (const float*)d_in[1];
    const float* conv_w  = (const float*)d_in[2];
    const float* conv_b  = (const float*)d_in[3];
    const float* dt_bias = (const float*)d_in[4];
    const float* A_log   = (const float*)d_in[5];
    const float* Dv      = (const float*)d_in[6];
    const float* norm_w  = (const float*)d_in[7];
    const float* W_out   = (const float*)d_in[8];
    float* out = (float*)d_out;

    char* ws = (char*)d_ws;
    size_t o = 0;
    float* zx   = (float*)(ws + o); o += (size_t)NTOK * DP * 4;                  // 143.7 MB
    float* S    = (float*)(ws + o); o += (size_t)BSZ * NH * NCH * HD * DS * 4;   // 67.1 MB
    float* dtv  = (float*)(ws + o); o += (size_t)NTOK * NH * 4;
    float* ldA  = (float*)(ws + o); o += (size_t)NTOK * NH * 4;
    float* csum = (float*)(ws + o); o += (size_t)BSZ * NH * NCH * 4;
    float* halo = (float*)(ws + o); o += (size_t)NRB * 3 * CD * 4;               // 3.5 MB
    // Aliases inside S (each dead before S's real producer/consumer needs it):
    ushort_t* Ah  = (ushort_t*)S;                                   // 16.8 MB (dead after GEMM1)
    ushort_t* W1t = (ushort_t*)((char*)S + (size_t)NTOK * DM * 2);  // 9.2 MB  (dead after GEMM1)
    ushort_t* Wot = (ushort_t*)S;                                   // 4.2 MB  (written after gate_rms)
    ushort_t* ynb = (ushort_t*)zx + 2 * XOFF;                       // bf16 y_norm in xBC slice, lda=2*DP

    // 1) bf16 conversions for GEMM1
    cvt_bf16<<<(NTOK * DM) / 1024, 256, 0, stream>>>(hidden, Ah);
    transpose_cvt<<<dim3(NPAD / 32, DM / 32), 256, 0, stream>>>(W_in, W1t, DM, DP, DP);
    // 2) zxbcdt = hidden @ W_in  (bf16 MFMA, fp32 out)
    gemm_bf16<<<dim3(NPAD / 128, NTOK / 128), 256, 0, stream>>>(
        Ah, W1t, zx, DM, DM, DM, DP, DP);
    // 3) conv halos + in-place causal conv + SiLU
    halo_save<<<(NRB * 3 * CD) / 256, 256, 0, stream>>>(zx, halo);
    conv_silu_inplace<<<dim3(CD / 256, NRB), 256, 0, stream>>>(zx, halo, conv_w, conv_b);
    // 4) dt in fp32 (bypasses bf16 GEMM on the exp-amplified path)
    dt_proc_fp32<<<NTOK / 8, 256, 0, stream>>>(hidden, W_in, dt_bias, A_log, dtv, ldA);
    // 5) chunk state contributions (overwrites Ah/W1t region — they're dead)
    phase1<<<BSZ * NH * NCH, 256, 0, stream>>>(zx, dtv, ldA, S, csum);
    // 6) cross-chunk recurrence
    phase2<<<BSZ * NH, 256, 0, stream>>>(S, csum);
    // 7) per-chunk outputs (overwrites S with y)
    phase3<<<BSZ * NH * NCH, 256, 0, stream>>>(zx, dtv, ldA, Dv, S);
    // 8) gate + RMSNorm -> bf16 y_norm into zx's xBC slice
    gate_rms<<<NTOK, 256, 0, stream>>>(zx, S, norm_w);
    // 9) W_out transpose (S fully dead now), then out = y_norm @ W_out
    transpose_cvt<<<dim3(DM / 32, DI / 32), 256, 0, stream>>>(W_out, Wot, DI, DM, DM);
    gemm_bf16<<<dim3(DM / 128, NTOK / 128), 256, 0, stream>>>(
        ynb, Wot, out, DI, 2 * DP, DI, DM, DM);
}